// Round 4
// baseline (5166.426 us; speedup 1.0000x reference)
//
#include <hip/hip_runtime.h>

typedef unsigned short u16;

#define NA 22      /* agents per graph */
#define FIN 32     /* input feature dim */

__device__ float b2f(u16 u) {
    return __uint_as_float(((unsigned int)u) << 16);
}

__device__ u16 f2b(float f) {
    unsigned int x = __float_as_uint(f);
    x = (x + 0x7fffu + ((x >> 16) & 1u)) >> 16;  /* round-nearest-even */
    return (u16)x;
}

/* One dense-GAT layer over this block's graph.
   xs holds the layer input [NA][K] (bf16 in LDS); on exit xs holds the
   relu(out + bias) result [NA][H*C]. hs is scratch for h=[NA][H*C].
   Weights/bias/attention vectors are fp32 in global memory. */
__device__ void gat_layer(const float* W, const float* av_src, const float* av_dst,
                          const float* bias, int K, int H, int C,
                          u16* xs, u16* hs, float* sv, float* dv, float* al)
{
    int COLS = H * C;
    int tid = threadIdx.x;
    int col, p, f, a, j, c, i;

    /* GEMM: hs[a][col] = sum_f xs[a][f] * W[f][col]
       K is even; read bf16 pairs as one u32 LDS access. */
    for (col = tid; col < COLS; col += 256) {
        float acc[NA];
        for (a = 0; a < NA; ++a) { acc[a] = 0.0f; }
        for (f = 0; f < K; f += 2) {
            float w0 = W[f * COLS + col];
            float w1 = W[(f + 1) * COLS + col];
            for (a = 0; a < NA; ++a) {
                unsigned int xx = *(const unsigned int*)(xs + a * K + f);
                float x0 = __uint_as_float(xx << 16);
                float x1 = __uint_as_float(xx & 0xffff0000u);
                acc[a] += x0 * w0 + x1 * w1;
            }
        }
        for (a = 0; a < NA; ++a) { hs[a * COLS + col] = f2b(acc[a]); }
    }
    __syncthreads();

    /* attention coefficients: sv[h*NA+a] = h_a . a_src, dv likewise */
    for (p = tid; p < 2 * H * NA; p += 256) {
        int which = p / (H * NA);
        int pair = p - which * H * NA;
        int hh = pair / NA;
        int aa = pair - hh * NA;
        float sum = 0.0f;
        for (c = 0; c < C; c += 2) {
            unsigned int hx = *(const unsigned int*)(hs + aa * COLS + hh * C + c);
            float h0 = __uint_as_float(hx << 16);
            float h1 = __uint_as_float(hx & 0xffff0000u);
            float v0, v1;
            if (which) { v0 = av_dst[hh * C + c]; v1 = av_dst[hh * C + c + 1]; }
            else       { v0 = av_src[hh * C + c]; v1 = av_src[hh * C + c + 1]; }
            sum += h0 * v0 + h1 * v1;
        }
        if (which) { dv[pair] = sum; } else { sv[pair] = sum; }
    }
    __syncthreads();

    /* softmax over sources j for each (head, dst i), leaky-relu(0.2) on logits */
    for (p = tid; p < H * NA; p += 256) {
        int hh = p / NA;
        float di = dv[p];
        float lg[NA];
        float mx = -1.0e30f;
        float ss = 0.0f;
        float inv;
        for (j = 0; j < NA; ++j) {
            float l = di + sv[hh * NA + j];
            if (l < 0.0f) { l = l * 0.2f; }
            lg[j] = l;
            if (l > mx) { mx = l; }
        }
        for (j = 0; j < NA; ++j) {
            float e = expf(lg[j] - mx);
            lg[j] = e;
            ss += e;
        }
        inv = 1.0f / ss;
        for (j = 0; j < NA; ++j) { al[p * NA + j] = lg[j] * inv; }
    }
    __syncthreads();

    /* aggregate: xs[i][col] = relu(bias[col] + sum_j al[h][i][j]*hs[j][col]) */
    for (col = tid; col < COLS; col += 256) {
        int hh = col / C;
        float acc[NA];
        float bv = bias[col];
        for (i = 0; i < NA; ++i) { acc[i] = 0.0f; }
        for (j = 0; j < NA; ++j) {
            float hv = b2f(hs[j * COLS + col]);
            for (i = 0; i < NA; ++i) {
                acc[i] += al[(hh * NA + i) * NA + j] * hv;
            }
        }
        for (i = 0; i < NA; ++i) {
            float v = acc[i] + bv;
            if (v < 0.0f) { v = 0.0f; }
            xs[i * COLS + col] = f2b(v);
        }
    }
    __syncthreads();
}

__global__ void pressgnn_kernel(const float* feats,
                                const float* W1, const float* as1, const float* ad1, const float* b1,
                                const float* W2, const float* as2, const float* ad2, const float* b2,
                                const float* W3, const float* as3, const float* ad3, const float* b3,
                                const float* Wc, const float* bc,
                                float* out)
{
    __shared__ u16  xs[NA * 512];
    __shared__ u16  hs[NA * 512];
    __shared__ float sv[4 * NA];
    __shared__ float dv[4 * NA];
    __shared__ float al[4 * NA * NA];
    __shared__ float pool[128];

    int g = blockIdx.x;
    int tid = threadIdx.x;
    int i, a, c;

    /* load this graph's features: [NA][FIN] fp32 -> bf16 LDS */
    for (i = tid; i < NA * FIN; i += 256) { xs[i] = f2b(feats[g * NA * FIN + i]); }
    __syncthreads();

    gat_layer(W1, as1, ad1, b1, FIN, 4, 128, xs, hs, sv, dv, al);
    gat_layer(W2, as2, ad2, b2, 512, 4, 128, xs, hs, sv, dv, al);
    gat_layer(W3, as3, ad3, b3, 512, 1, 128, xs, hs, sv, dv, al);
    /* xs now holds [NA][128], relu'd (H=1: head-mean is identity) */

    /* global mean pool over agents + final linear 128->1 */
    if (tid < 128) {
        float s = 0.0f;
        for (a = 0; a < NA; ++a) { s += b2f(xs[a * 128 + tid]); }
        pool[tid] = (s / 22.0f) * Wc[tid];
    }
    __syncthreads();
    if (tid == 0) {
        float t = 0.0f;
        for (c = 0; c < 128; ++c) { t += pool[c]; }
        out[g] = t + bc[0];
    }
}

extern "C" void kernel_launch(void* const* d_in, const int* in_sizes, int n_in,
                              void* d_out, int out_size, void* d_ws, size_t ws_size,
                              hipStream_t stream) {
    const float* feats = (const float*)d_in[0];
    const float* W1  = (const float*)d_in[1];
    const float* as1 = (const float*)d_in[2];
    const float* ad1 = (const float*)d_in[3];
    const float* b1  = (const float*)d_in[4];
    const float* W2  = (const float*)d_in[5];
    const float* as2 = (const float*)d_in[6];
    const float* ad2 = (const float*)d_in[7];
    const float* b2  = (const float*)d_in[8];
    const float* W3  = (const float*)d_in[9];
    const float* as3 = (const float*)d_in[10];
    const float* ad3 = (const float*)d_in[11];
    const float* b3  = (const float*)d_in[12];
    const float* Wc  = (const float*)d_in[13];
    const float* bc  = (const float*)d_in[14];
    float* out = (float*)d_out;

    /* one block per graph; graph count == output element count (B*T = 4096) */
    pressgnn_kernel<<<dim3(out_size), dim3(256), 0, stream>>>(
        feats, W1, as1, ad1, b1,
        W2, as2, ad2, b2,
        W3, as3, ad3, b3,
        Wc, bc, out);
}

// Round 5
// 403.253 us; speedup vs baseline: 12.8119x; 12.8119x over previous
//
#include <hip/hip_runtime.h>

typedef unsigned short u16;
typedef short bf16x8 __attribute__((ext_vector_type(8)));
typedef float f32x4  __attribute__((ext_vector_type(4)));

#define NA 22      /* agents per graph */
#define FIN 32     /* input feature dim */

/* d_ws layout (u16 elements): W1s [0,16384) W2s [16384,278528) W3s [278528,344064) */
#define W1_OFF 0
#define W2_OFF 16384
#define W3_OFF 278528
#define WS_TOTAL 344064

__device__ float b2f(u16 u) {
    return __uint_as_float(((unsigned int)u) << 16);
}

__device__ u16 f2b(float f) {
    unsigned int x = __float_as_uint(f);
    x = (x + 0x7fffu + ((x >> 16) & 1u)) >> 16;  /* round-nearest-even */
    return (u16)x;
}

/* Swizzle fp32 W [K][N] -> bf16 MFMA B-fragment layout:
   frag(kt,nt) is 512 u16: lane l (0..63), elem j (0..7) holds
   W[kt*32 + (l>>4)*8 + j][nt*16 + (l&15)]. */
__global__ void swizzle_kernel(const float* W1, const float* W2, const float* W3, u16* ws)
{
    int t = blockIdx.x * 256 + threadIdx.x;
    const float* W;
    int NT, N, loc;
    if (t < W2_OFF)         { W = W1; NT = 32; N = 512; loc = t; }
    else if (t < W3_OFF)    { W = W2; NT = 32; N = 512; loc = t - W2_OFF; }
    else if (t < WS_TOTAL)  { W = W3; NT = 8;  N = 128; loc = t - W3_OFF; }
    else { return; }
    int tile = loc >> 9;
    int r    = loc & 511;
    int lane = r >> 3;
    int j    = r & 7;
    int kt = tile / NT;
    int nt = tile - kt * NT;
    int k = kt * 32 + (lane >> 4) * 8 + j;
    int n = nt * 16 + (lane & 15);
    ws[t] = f2b(W[k * N + n]);
}

/* hs[a][col] = sum_f xs[a][f] * W[f][col] via mfma_f32_16x16x32_bf16.
   xs: [32][K] bf16 LDS (rows 22..31 zero). hs: [22][COLS] bf16 LDS.
   Wsw: pre-swizzled B-fragments. 4 waves; wave owns NT/4 n-tiles. */
__device__ __forceinline__ void mfma_gemm(const u16* xs, u16* hs, const u16* Wsw,
                                          int K, int COLS)
{
    int NT  = COLS >> 4;
    int KT  = K >> 5;
    int NTW = NT >> 2;                 /* n-tiles per wave: 8, 8, 2 */
    int tid  = threadIdx.x;
    int wave = tid >> 6, lane = tid & 63;
    int quad = lane >> 4, lm = lane & 15;

    f32x4 acc[2][8];
    for (int mt = 0; mt < 2; ++mt) {
        for (int n = 0; n < NTW; ++n) {
            f32x4 z = {0.f, 0.f, 0.f, 0.f};
            acc[mt][n] = z;
        }
    }
    for (int kt = 0; kt < KT; ++kt) {
        bf16x8 a0 = *(const bf16x8*)(xs + lm * K + kt * 32 + quad * 8);
        bf16x8 a1 = *(const bf16x8*)(xs + (16 + lm) * K + kt * 32 + quad * 8);
        #pragma unroll
        for (int n = 0; n < NTW; ++n) {
            int nt = wave * NTW + n;
            bf16x8 b = *(const bf16x8*)(Wsw + ((kt * NT + nt) << 9) + (lane << 3));
            acc[0][n] = __builtin_amdgcn_mfma_f32_16x16x32_bf16(a0, b, acc[0][n], 0, 0, 0);
            acc[1][n] = __builtin_amdgcn_mfma_f32_16x16x32_bf16(a1, b, acc[1][n], 0, 0, 0);
        }
    }
    /* D layout: row = quad*4 + r (+16 for mt=1), col = nt*16 + lm */
    for (int n = 0; n < NTW; ++n) {
        int nt = wave * NTW + n;
        for (int mt = 0; mt < 2; ++mt) {
            for (int r = 0; r < 4; ++r) {
                int row = mt * 16 + quad * 4 + r;
                if (row < NA) { hs[row * COLS + nt * 16 + lm] = f2b(acc[mt][n][r]); }
            }
        }
    }
}

__device__ __forceinline__ void gat_layer(const u16* Wsw, const float* avs, const float* avd,
                                          const float* bias, int K, int H, int C,
                                          u16* xs, u16* hs, float* sv, float* dv, float* al)
{
    int COLS = H * C;
    int tid = threadIdx.x;

    mfma_gemm(xs, hs, Wsw, K, COLS);
    __syncthreads();

    /* attention coefficients: sv[h*NA+a] = h_a . a_src, dv likewise */
    if (tid < 2 * H * NA) {
        int which = tid / (H * NA);
        int pair = tid - which * (H * NA);
        int hh = pair / NA;
        int aa = pair - hh * NA;
        const float* av = which ? avd : avs;
        float sum = 0.0f;
        for (int c = 0; c < C; c += 2) {
            unsigned int hx = *(const unsigned int*)(hs + aa * COLS + hh * C + c);
            sum += __uint_as_float(hx << 16) * av[hh * C + c]
                 + __uint_as_float(hx & 0xffff0000u) * av[hh * C + c + 1];
        }
        if (which) { dv[pair] = sum; } else { sv[pair] = sum; }
    }
    __syncthreads();

    /* softmax over sources j, leaky-relu(0.2) on logits */
    if (tid < H * NA) {
        int hh = tid / NA;
        float di = dv[tid];
        float lg[NA];
        float mx = -1.0e30f;
        float ss = 0.0f;
        for (int j = 0; j < NA; ++j) {
            float l = di + sv[hh * NA + j];
            if (l < 0.0f) { l = l * 0.2f; }
            lg[j] = l;
            if (l > mx) { mx = l; }
        }
        for (int j = 0; j < NA; ++j) {
            float e = expf(lg[j] - mx);
            lg[j] = e;
            ss += e;
        }
        float inv = 1.0f / ss;
        for (int j = 0; j < NA; ++j) { al[tid * NA + j] = lg[j] * inv; }
    }
    __syncthreads();

    /* aggregate: xs[i][c] = relu(bias[c] + sum_j al[h][i][j]*hs[j][c]); 2 cols/thread */
    if (tid * 2 < COLS) {
        int c0 = tid * 2;
        int hh = c0 / C;
        float acc0[NA], acc1[NA];
        for (int i = 0; i < NA; ++i) { acc0[i] = 0.0f; acc1[i] = 0.0f; }
        const float* ar = al + hh * NA * NA;
        for (int j = 0; j < NA; ++j) {
            unsigned int hx = *(const unsigned int*)(hs + j * COLS + c0);
            float h0 = __uint_as_float(hx << 16);
            float h1 = __uint_as_float(hx & 0xffff0000u);
            #pragma unroll
            for (int i = 0; i < NA; ++i) {
                float a = ar[i * NA + j];
                acc0[i] += a * h0;
                acc1[i] += a * h1;
            }
        }
        float bv0 = bias[c0];
        float bv1 = bias[c0 + 1];
        for (int i = 0; i < NA; ++i) {
            float v0 = acc0[i] + bv0; if (v0 < 0.0f) { v0 = 0.0f; }
            float v1 = acc1[i] + bv1; if (v1 < 0.0f) { v1 = 0.0f; }
            unsigned int packed = (unsigned int)f2b(v0) | (((unsigned int)f2b(v1)) << 16);
            *(unsigned int*)(xs + i * COLS + c0) = packed;
        }
    }
    __syncthreads();
}

__global__ void pressgnn_kernel(const float* feats, const u16* ws,
                                const float* as1, const float* ad1, const float* b1,
                                const float* as2, const float* ad2, const float* b2,
                                const float* as3, const float* ad3, const float* b3,
                                const float* Wc, const float* bc,
                                float* out)
{
    __shared__ u16  xs[32 * 512];        /* 32 KB: input, rows 22..31 stay zero */
    __shared__ u16  hs[NA * 512];        /* 22 KB: GEMM output */
    __shared__ float sv[4 * NA];
    __shared__ float dv[4 * NA];
    __shared__ float al[4 * NA * NA];    /* also reused as pool scratch */

    int g = blockIdx.x;
    int tid = threadIdx.x;
    int i;

    /* zero all of xs (covers pad rows for every layer stride), then load feats */
    for (i = tid; i < 32 * 512 / 2; i += 256) { ((unsigned int*)xs)[i] = 0u; }
    __syncthreads();
    for (i = tid; i < NA * FIN; i += 256) { xs[i] = f2b(feats[g * NA * FIN + i]); }
    __syncthreads();

    gat_layer(ws + W1_OFF, as1, ad1, b1, 32,  4, 128, xs, hs, sv, dv, al);
    gat_layer(ws + W2_OFF, as2, ad2, b2, 512, 4, 128, xs, hs, sv, dv, al);
    gat_layer(ws + W3_OFF, as3, ad3, b3, 512, 1, 128, xs, hs, sv, dv, al);
    /* xs now holds [NA][128] relu'd (H=1: head-mean is identity) */

    /* global mean pool over agents + final linear 128->1 (al reused as scratch) */
    if (tid < 128) {
        float s = 0.0f;
        for (int a = 0; a < NA; ++a) { s += b2f(xs[a * 128 + tid]); }
        al[tid] = (s / 22.0f) * Wc[tid];
    }
    __syncthreads();
    if (tid == 0) {
        float t = 0.0f;
        for (int c = 0; c < 128; ++c) { t += al[c]; }
        out[g] = t + bc[0];
    }
}

extern "C" void kernel_launch(void* const* d_in, const int* in_sizes, int n_in,
                              void* d_out, int out_size, void* d_ws, size_t ws_size,
                              hipStream_t stream) {
    const float* feats = (const float*)d_in[0];
    const float* W1  = (const float*)d_in[1];
    const float* as1 = (const float*)d_in[2];
    const float* ad1 = (const float*)d_in[3];
    const float* b1  = (const float*)d_in[4];
    const float* W2  = (const float*)d_in[5];
    const float* as2 = (const float*)d_in[6];
    const float* ad2 = (const float*)d_in[7];
    const float* b2  = (const float*)d_in[8];
    const float* W3  = (const float*)d_in[9];
    const float* as3 = (const float*)d_in[10];
    const float* ad3 = (const float*)d_in[11];
    const float* b3  = (const float*)d_in[12];
    const float* Wc  = (const float*)d_in[13];
    const float* bc  = (const float*)d_in[14];
    float* out = (float*)d_out;
    u16* ws = (u16*)d_ws;

    /* per-launch weight swizzle into d_ws (d_ws is re-poisoned before every call) */
    swizzle_kernel<<<dim3((WS_TOTAL + 255) / 256), dim3(256), 0, stream>>>(W1, W2, W3, ws);

    /* one block per graph; graph count == output element count (B*T = 4096) */
    pressgnn_kernel<<<dim3(out_size), dim3(256), 0, stream>>>(
        feats, ws,
        as1, ad1, b1,
        as2, ad2, b2,
        as3, ad3, b3,
        Wc, bc, out);
}

// Round 6
// 368.423 us; speedup vs baseline: 14.0231x; 1.0945x over previous
//
#include <hip/hip_runtime.h>

typedef unsigned short u16;
typedef short bf16x8 __attribute__((ext_vector_type(8)));
typedef float f32x4  __attribute__((ext_vector_type(4)));

#define NA 22       /* agents per graph */
#define FIN 32      /* input feature dim */
#define XS_STR 520  /* padded LDS row stride (elements): 1040B = 65*16B, bank-conflict-free */

/* d_ws layout (u16 elements): W1s [0,16384) W2s [16384,278528) W3s [278528,344064) */
#define W1_OFF 0
#define W2_OFF 16384
#define W3_OFF 278528
#define WS_TOTAL 344064

__device__ float b2f(u16 u) {
    return __uint_as_float(((unsigned int)u) << 16);
}

__device__ u16 f2b(float f) {
    unsigned int x = __float_as_uint(f);
    x = (x + 0x7fffu + ((x >> 16) & 1u)) >> 16;  /* round-nearest-even */
    return (u16)x;
}

/* Swizzle fp32 W [K][N] -> bf16 MFMA B-fragment layout:
   frag(kt,nt) is 512 u16: lane l (0..63), elem j (0..7) holds
   W[kt*32 + (l>>4)*8 + j][nt*16 + (l&15)]. */
__global__ void swizzle_kernel(const float* W1, const float* W2, const float* W3, u16* ws)
{
    int t = blockIdx.x * 256 + threadIdx.x;
    const float* W;
    int NT, N, loc;
    if (t < W2_OFF)         { W = W1; NT = 32; N = 512; loc = t; }
    else if (t < W3_OFF)    { W = W2; NT = 32; N = 512; loc = t - W2_OFF; }
    else if (t < WS_TOTAL)  { W = W3; NT = 8;  N = 128; loc = t - W3_OFF; }
    else { return; }
    int tile = loc >> 9;
    int r    = loc & 511;
    int lane = r >> 3;
    int j    = r & 7;
    int kt = tile / NT;
    int nt = tile - kt * NT;
    int k = kt * 32 + (lane >> 4) * 8 + j;
    int n = nt * 16 + (lane & 15);
    ws[t] = f2b(W[k * N + n]);
}

/* hs[a][col] = sum_f xs[a][f] * W[f][col] via mfma_f32_16x16x32_bf16.
   xs: [NA][XS_STR] bf16 LDS. hs: [NA][XS_STR] bf16 LDS.
   M=22 split into m-tiles {0..15},{16..21}; the 2nd tile's lanes lm>=6 read
   row lm instead (garbage A-row only corrupts its own D-row, never stored).
   Wsw: pre-swizzled B-fragments. 4 waves; wave owns NT/4 n-tiles. */
__device__ __forceinline__ void mfma_gemm(const u16* xs, u16* hs, const u16* Wsw,
                                          int K, int COLS)
{
    int NT  = COLS >> 4;
    int KT  = K >> 5;
    int NTW = NT >> 2;                 /* n-tiles per wave: 8, 8, 2 */
    int tid  = threadIdx.x;
    int wave = tid >> 6, lane = tid & 63;
    int quad = lane >> 4, lm = lane & 15;

    int r1 = 16 + lm;
    if (r1 >= NA) { r1 = lm; }         /* safe dummy row for pad lanes */
    const u16* a0base = xs + lm * XS_STR;
    const u16* a1base = xs + r1 * XS_STR;

    f32x4 acc[2][8];
    for (int mt = 0; mt < 2; ++mt) {
        for (int n = 0; n < NTW; ++n) {
            f32x4 z = {0.f, 0.f, 0.f, 0.f};
            acc[mt][n] = z;
        }
    }
    for (int kt = 0; kt < KT; ++kt) {
        bf16x8 a0 = *(const bf16x8*)(a0base + kt * 32 + quad * 8);
        bf16x8 a1 = *(const bf16x8*)(a1base + kt * 32 + quad * 8);
        #pragma unroll
        for (int n = 0; n < NTW; ++n) {
            int nt = wave * NTW + n;
            bf16x8 b = *(const bf16x8*)(Wsw + ((kt * NT + nt) << 9) + (lane << 3));
            acc[0][n] = __builtin_amdgcn_mfma_f32_16x16x32_bf16(a0, b, acc[0][n], 0, 0, 0);
            acc[1][n] = __builtin_amdgcn_mfma_f32_16x16x32_bf16(a1, b, acc[1][n], 0, 0, 0);
        }
    }
    /* D layout: row = mt*16 + quad*4 + r, col = nt*16 + lm */
    for (int n = 0; n < NTW; ++n) {
        int nt = wave * NTW + n;
        for (int mt = 0; mt < 2; ++mt) {
            for (int r = 0; r < 4; ++r) {
                int row = mt * 16 + quad * 4 + r;
                if (row < NA) { hs[row * XS_STR + nt * 16 + lm] = f2b(acc[mt][n][r]); }
            }
        }
    }
}

__device__ __forceinline__ void gat_layer(const u16* Wsw, const float* avs, const float* avd,
                                          const float* bias, int K, int H, int C,
                                          u16* xs, u16* hs, float* sv, float* dv, float* al)
{
    int COLS = H * C;
    int tid = threadIdx.x;

    mfma_gemm(xs, hs, Wsw, K, COLS);
    __syncthreads();

    /* attention coefficients: sv[h*NA+a] = h_a . a_src, dv likewise */
    if (tid < 2 * H * NA) {
        int which = tid / (H * NA);
        int pair = tid - which * (H * NA);
        int hh = pair / NA;
        int aa = pair - hh * NA;
        const float* av = which ? avd : avs;
        float sum = 0.0f;
        for (int c = 0; c < C; c += 2) {
            unsigned int hx = *(const unsigned int*)(hs + aa * XS_STR + hh * C + c);
            sum += __uint_as_float(hx << 16) * av[hh * C + c]
                 + __uint_as_float(hx & 0xffff0000u) * av[hh * C + c + 1];
        }
        if (which) { dv[pair] = sum; } else { sv[pair] = sum; }
    }
    __syncthreads();

    /* softmax over sources j, leaky-relu(0.2) on logits */
    if (tid < H * NA) {
        int hh = tid / NA;
        float di = dv[tid];
        float lg[NA];
        float mx = -1.0e30f;
        float ss = 0.0f;
        for (int j = 0; j < NA; ++j) {
            float l = di + sv[hh * NA + j];
            if (l < 0.0f) { l = l * 0.2f; }
            lg[j] = l;
            if (l > mx) { mx = l; }
        }
        for (int j = 0; j < NA; ++j) {
            float e = expf(lg[j] - mx);
            lg[j] = e;
            ss += e;
        }
        float inv = 1.0f / ss;
        for (int j = 0; j < NA; ++j) { al[tid * NA + j] = lg[j] * inv; }
    }
    __syncthreads();

    /* aggregate: xs[i][c] = relu(bias[c] + sum_j al[h][i][j]*hs[j][c]); 2 cols/thread */
    if (tid * 2 < COLS) {
        int c0 = tid * 2;
        int hh = c0 / C;
        float acc0[NA], acc1[NA];
        for (int i = 0; i < NA; ++i) { acc0[i] = 0.0f; acc1[i] = 0.0f; }
        const float* ar = al + hh * NA * NA;
        for (int j = 0; j < NA; ++j) {
            unsigned int hx = *(const unsigned int*)(hs + j * XS_STR + c0);
            float h0 = __uint_as_float(hx << 16);
            float h1 = __uint_as_float(hx & 0xffff0000u);
            #pragma unroll
            for (int i = 0; i < NA; ++i) {
                float a = ar[i * NA + j];
                acc0[i] += a * h0;
                acc1[i] += a * h1;
            }
        }
        float bv0 = bias[c0];
        float bv1 = bias[c0 + 1];
        for (int i = 0; i < NA; ++i) {
            float v0 = acc0[i] + bv0; if (v0 < 0.0f) { v0 = 0.0f; }
            float v1 = acc1[i] + bv1; if (v1 < 0.0f) { v1 = 0.0f; }
            unsigned int packed = (unsigned int)f2b(v0) | (((unsigned int)f2b(v1)) << 16);
            *(unsigned int*)(xs + i * XS_STR + c0) = packed;
        }
    }
    __syncthreads();
}

__global__ void pressgnn_kernel(const float* feats, const u16* ws,
                                const float* as1, const float* ad1, const float* b1,
                                const float* as2, const float* ad2, const float* b2,
                                const float* as3, const float* ad3, const float* b3,
                                const float* Wc, const float* bc,
                                float* out)
{
    __shared__ u16  xs[NA * XS_STR];     /* 22880 B */
    __shared__ u16  hs[NA * XS_STR];     /* 22880 B */
    __shared__ float sv[4 * NA];
    __shared__ float dv[4 * NA];
    __shared__ float al[4 * NA * NA];    /* also reused as pool scratch */
    /* total ~54.2 KB -> 3 blocks/CU */

    int g = blockIdx.x;
    int tid = threadIdx.x;

    /* load this graph's features: [NA][FIN] fp32 -> bf16 LDS (padded stride) */
    for (int i = tid; i < NA * FIN; i += 256) {
        int row = i >> 5;
        int col = i & 31;
        xs[row * XS_STR + col] = f2b(feats[g * NA * FIN + i]);
    }
    __syncthreads();

    gat_layer(ws + W1_OFF, as1, ad1, b1, 32,  4, 128, xs, hs, sv, dv, al);
    gat_layer(ws + W2_OFF, as2, ad2, b2, 512, 4, 128, xs, hs, sv, dv, al);
    gat_layer(ws + W3_OFF, as3, ad3, b3, 512, 1, 128, xs, hs, sv, dv, al);
    /* xs now holds [NA][128] relu'd (H=1: head-mean is identity) */

    /* global mean pool over agents + final linear 128->1 (al reused as scratch) */
    if (tid < 128) {
        float s = 0.0f;
        for (int a = 0; a < NA; ++a) { s += b2f(xs[a * XS_STR + tid]); }
        al[tid] = (s / 22.0f) * Wc[tid];
    }
    __syncthreads();
    if (tid == 0) {
        float t = 0.0f;
        for (int c = 0; c < 128; ++c) { t += al[c]; }
        out[g] = t + bc[0];
    }
}

extern "C" void kernel_launch(void* const* d_in, const int* in_sizes, int n_in,
                              void* d_out, int out_size, void* d_ws, size_t ws_size,
                              hipStream_t stream) {
    const float* feats = (const float*)d_in[0];
    const float* W1  = (const float*)d_in[1];
    const float* as1 = (const float*)d_in[2];
    const float* ad1 = (const float*)d_in[3];
    const float* b1  = (const float*)d_in[4];
    const float* W2  = (const float*)d_in[5];
    const float* as2 = (const float*)d_in[6];
    const float* ad2 = (const float*)d_in[7];
    const float* b2  = (const float*)d_in[8];
    const float* W3  = (const float*)d_in[9];
    const float* as3 = (const float*)d_in[10];
    const float* ad3 = (const float*)d_in[11];
    const float* b3  = (const float*)d_in[12];
    const float* Wc  = (const float*)d_in[13];
    const float* bc  = (const float*)d_in[14];
    float* out = (float*)d_out;
    u16* ws = (u16*)d_ws;

    /* per-launch weight swizzle into d_ws (d_ws is re-poisoned before every call) */
    swizzle_kernel<<<dim3((WS_TOTAL + 255) / 256), dim3(256), 0, stream>>>(W1, W2, W3, ws);

    /* one block per graph; graph count == output element count (B*T = 4096) */
    pressgnn_kernel<<<dim3(out_size), dim3(256), 0, stream>>>(
        feats, ws,
        as1, ad1, b1,
        as2, ad2, b2,
        as3, ad3, b3,
        Wc, bc, out);
}